// Round 9
// baseline (134.315 us; speedup 1.0000x reference)
//
#include <hip/hip_runtime.h>
#include <hip/hip_bf16.h>
#include <stdint.h>

// KAN layer fused kernel, MI355X (gfx950) — V9: V8 + stage-transposed spline (ILP fix).
// out[M=65536, N=256] (fp32) = A[M, K=256] @ W^T, where
//   A[m,k] = c0[k]*B0(tanh(x[m,k])) + c1[k]*B1(tanh(x[m,k]))  (on the fly -> bf16)
//   W = outer_coeffs [N,K] fp32 -> bf16 (conv_w, SWIZZLED layout, into d_ws)
//
// Ladder: V1 58 V2 87 V3 44 V4/5/6/7 119-181 (phase-split spills) V8 43.3 (clean:
//   VGPR 124, FETCH 33.6MB; halved LDS+MFMA vs V3 bought only 1us).
// V8 diagnosis: VALUBusy 35% @ 2 waves/SIMD = 1125 VALU-cyc/iter vs 6450-cyc wall.
//   Per-wave VALU issue ~17.5% ~= 1 op / 11 cyc => the spline is a SERIALIZED
//   dependent chain (compiler emitted the 8 inner_evals back-to-back; at 124 VGPR
//   it can't interleave 8 chains' temps). Latency-bound, not throughput-bound.
// V9 = V8 with the spline hand-transposed into stages across all 8 evals
//   (e[8] -> u[8] -> per-knot B0[8]/B1[8] fma accumulation; static indices only),
//   B-reads moved after the spline (frees 32 regs during it; LDS latency hides
//   under the final combine+pack), branchless x prefetch. Same math to <=1 ulp
//   fp32 (u = fma(-7,rcp,7) == (t+1)*3.5 regrouped; fma-tree == the - 4w +6w tree).

typedef __attribute__((ext_vector_type(8))) short short8;    // 8 bf16 = 4 VGPR (MFMA A/B frag)
typedef __attribute__((ext_vector_type(16))) float f32x16;   // 32x32 MFMA C/D frag

__device__ __forceinline__ uint16_t f2bf(float f) {
    union { float f; uint32_t u; } v; v.f = f;
    uint32_t r = v.u + 0x7FFFu + ((v.u >> 16) & 1u);  // RNE
    return (uint16_t)(r >> 16);
}

// Pack 2 floats -> 2 bf16 (RNE) in one v_cvt_pk_bf16_f32 (compiler-emitted)
__device__ __forceinline__ uint32_t pack_bf2(float lo, float hi) {
    __hip_bfloat162 h = __float22bfloat162_rn(make_float2(lo, hi));
    union { __hip_bfloat162 h; uint32_t u; } v; v.h = h;
    return v.u;
}

__device__ __forceinline__ void load_lds16(const void* g, void* l) {
    __builtin_amdgcn_global_load_lds(
        (const __attribute__((address_space(1))) uint32_t*)g,
        (__attribute__((address_space(3))) uint32_t*)l, 16, 0, 0);
}

// W fp32 -> bf16 into the XOR-SWIZZLED layout kan_fused's ds_reads expect:
//   value W[row][col] lands at byte  row*512 + ((col*2) ^ ((row&7)<<4)).
__global__ void conv_w(const float4* __restrict__ wf, char* __restrict__ o) {
    const int i = blockIdx.x * blockDim.x + threadIdx.x;  // 0..16383
    const float4 v = wf[i];
    uint2 r;
    r.x = (uint32_t)f2bf(v.x) | ((uint32_t)f2bf(v.y) << 16);
    r.y = (uint32_t)f2bf(v.z) | ((uint32_t)f2bf(v.w) << 16);
    const int row = i >> 6;           // 64 threads per 256-float row
    const int cb  = (i & 63) << 3;    // byte col within row, 8-aligned
    *(uint2*)(o + row * 512 + (cb ^ ((row & 7) << 4))) = r;
}

// Block: 512 threads = 8 waves, grid 256 -> 1 block/CU (LDS-limited, 2 waves/SIMD).
// Wave w owns rows [bid*256 + w*32, +32), all 256 cols as 8 n-tiles of 32x32.
// Mappings (HW-verified V8): A: m=lane&31, k=(lane>>5)*8+e; B: n=lane&31, same k;
//   C/D: col=lane&31, row=(r&3)+8*(r>>2)+4*(lane>>5), r in [0,16).
__global__ void __launch_bounds__(512, 2) kan_fused(const float* __restrict__ x,
                                                    const float* __restrict__ ic,
                                                    const char* __restrict__ wb,
                                                    float* __restrict__ out)
{
    __shared__ __align__(16) char smem[133120];
    char*   Wlds = smem;                       // [256 rows][512 B], swizzled
    float2* C2   = (float2*)(smem + 131072);   // (c0,c1) per channel

    const int t    = threadIdx.x;
    const int lane = t & 63;
    const int w    = t >> 6;
    const int col  = lane & 31;     // A row-in-strip / B n-in-tile / C col
    const int half = lane >> 5;     // k-half selector (8 k each)
    const int swz  = (col & 7) << 4;

    const int mb = blockIdx.x * 256 + w * 32;   // wave's first output row
    const float* xp = x + (size_t)(mb + col) * 256 + half * 8;

    // x for kk=0, issued FIRST (pre-DMA: in-order vmcnt means its wait never
    // forces the W DMA to drain; barrier covers completeness anyway)
    float4 xa = *(const float4*)(xp);
    float4 xb = *(const float4*)(xp + 4);

    // coeff table (tiny, L2-hot)
    if (t < 256) C2[t] = make_float2(ic[t * 5 + 0], ic[t * 5 + 1]);

    // Stage all 128 KB of (pre-swizzled) W linearly: 16 issues x 8 waves x 1 KB.
    #pragma unroll
    for (int it = 0; it < 16; ++it) {
        const int base = ((it * 8 + w) << 10) + lane * 16;
        load_lds16(wb + base, Wlds + base);
    }
    __syncthreads();   // the ONLY barrier: W staged + C2 visible

    f32x16 acc[8];
    #pragma unroll
    for (int j = 0; j < 8; ++j)
        #pragma unroll
        for (int r = 0; r < 16; ++r)
            acc[j][r] = 0.0f;

    #pragma unroll 1
    for (int kk = 0; kk < 16; ++kk) {
        // --- next-iter x prefetch, branchless (kk=15 harmlessly reloads iter 0) ---
        const int knext = (kk + 1) & 15;
        float4 xa_n = *(const float4*)(xp + knext * 16);
        float4 xb_n = *(const float4*)(xp + knext * 16 + 4);

        // --- coeffs for this lane's 8 channels (LDS broadcast) ---
        const int gk = kk * 16 + half * 8;
        const float4 cA = *(const float4*)(&C2[gk + 0]);
        const float4 cB = *(const float4*)(&C2[gk + 2]);
        const float4 cC = *(const float4*)(&C2[gk + 4]);
        const float4 cD = *(const float4*)(&C2[gk + 6]);

        // ===== stage-transposed spline: 8 independent lanes per stage =====
        float xv8[8] = {xa.x, xa.y, xa.z, xa.w, xb.x, xb.y, xb.z, xb.w};

        // stage 1: e = exp(2x)   (8 independent trans chains)
        float ee[8];
        #pragma unroll
        for (int i = 0; i < 8; ++i) ee[i] = __expf(2.0f * xv8[i]);

        // stage 2: u = (tanh(x)+1)*3.5 = 7 - 7*rcp(e+1)
        float uu[8];
        #pragma unroll
        for (int i = 0; i < 8; ++i)
            uu[i] = fmaf(-7.0f, __builtin_amdgcn_rcpf(ee[i] + 1.0f), 7.0f);

        // stage 3: accumulate B0/B1 over knots j=0..5 (cardinal cubic weights)
        //   B0 weights {1,-4,6,-4,1,0}, B1 weights {0,1,-4,6,-4,1}
        float B0[8], B1[8];
        #pragma unroll
        for (int i = 0; i < 8; ++i) {
            float m = fmaxf(uu[i], 0.0f);          B0[i] = m * m * m;
        }
        #pragma unroll
        for (int i = 0; i < 8; ++i) {
            float m = fmaxf(uu[i] - 1.0f, 0.0f);   float m3 = m * m * m;
            B0[i] = fmaf(-4.0f, m3, B0[i]);        B1[i] = m3;
        }
        #pragma unroll
        for (int i = 0; i < 8; ++i) {
            float m = fmaxf(uu[i] - 2.0f, 0.0f);   float m3 = m * m * m;
            B0[i] = fmaf(6.0f, m3, B0[i]);         B1[i] = fmaf(-4.0f, m3, B1[i]);
        }
        #pragma unroll
        for (int i = 0; i < 8; ++i) {
            float m = fmaxf(uu[i] - 3.0f, 0.0f);   float m3 = m * m * m;
            B0[i] = fmaf(-4.0f, m3, B0[i]);        B1[i] = fmaf(6.0f, m3, B1[i]);
        }
        #pragma unroll
        for (int i = 0; i < 8; ++i) {
            float m = fmaxf(uu[i] - 4.0f, 0.0f);   float m3 = m * m * m;
            B0[i] = B0[i] + m3;                    B1[i] = fmaf(-4.0f, m3, B1[i]);
        }
        #pragma unroll
        for (int i = 0; i < 8; ++i) {
            float m = fmaxf(uu[i] - 5.0f, 0.0f);   B1[i] = B1[i] + m * m * m;
        }

        // --- B frags from LDS now (latency hides under combine+pack below) ---
        const int cw = (kk * 32 + half * 16) ^ swz;
        short8 b[8];
        #pragma unroll
        for (int j = 0; j < 8; ++j)
            b[j] = *(const short8*)(Wlds + ((j * 32 + col) << 9) + cw);

        // stage 4: combine with per-channel coeffs, scale 1/6
        float vv[8];
        vv[0] = (cA.x * B0[0] + cA.y * B1[0]) * (1.0f / 6.0f);
        vv[1] = (cA.z * B0[1] + cA.w * B1[1]) * (1.0f / 6.0f);
        vv[2] = (cB.x * B0[2] + cB.y * B1[2]) * (1.0f / 6.0f);
        vv[3] = (cB.z * B0[3] + cB.w * B1[3]) * (1.0f / 6.0f);
        vv[4] = (cC.x * B0[4] + cC.y * B1[4]) * (1.0f / 6.0f);
        vv[5] = (cC.z * B0[5] + cC.w * B1[5]) * (1.0f / 6.0f);
        vv[6] = (cD.x * B0[6] + cD.y * B1[6]) * (1.0f / 6.0f);
        vv[7] = (cD.z * B0[7] + cD.w * B1[7]) * (1.0f / 6.0f);

        union { short8 v; uint32_t u[4]; } af;
        af.u[0] = pack_bf2(vv[0], vv[1]);
        af.u[1] = pack_bf2(vv[2], vv[3]);
        af.u[2] = pack_bf2(vv[4], vv[5]);
        af.u[3] = pack_bf2(vv[6], vv[7]);

        // --- MFMA sweep: 8 x 32x32x16 (independent acc chains) ---
        #pragma unroll
        for (int j = 0; j < 8; ++j)
            acc[j] = __builtin_amdgcn_mfma_f32_32x32x16_bf16(af.v, b[j], acc[j], 0, 0, 0);

        xa = xa_n; xb = xb_n;
    }

    // --- epilogue: C/D layout col=lane&31, row=(r&3)+8*(r>>2)+4*half ---
    float* op = out + (size_t)(mb + 4 * half) * 256 + col;
    #pragma unroll
    for (int j = 0; j < 8; ++j) {
        #pragma unroll
        for (int r = 0; r < 16; ++r)
            op[(size_t)((r & 3) + 8 * (r >> 2)) * 256 + j * 32] = acc[j][r];
    }
}

extern "C" void kernel_launch(void* const* d_in, const int* in_sizes, int n_in,
                              void* d_out, int out_size, void* d_ws, size_t ws_size,
                              hipStream_t stream) {
    const float* x  = (const float*)d_in[0];   // [16,4096,256] fp32
    const float* ic = (const float*)d_in[1];   // [256,5] fp32
    const float* oc = (const float*)d_in[2];   // [256,256] fp32
    char* wb = (char*)d_ws;                    // 128 KB bf16 swizzled copy of W

    conv_w<<<64, 256, 0, stream>>>((const float4*)oc, wb);
    kan_fused<<<256, 512, 0, stream>>>(x, ic, wb, (float*)d_out);
}